// Round 1
// baseline (614.733 us; speedup 1.0000x reference)
//
#include <hip/hip_runtime.h>
#include <hip/hip_bf16.h>

// Shapes (fixed by the reference): T=1024, B=8, D=1024, H=16, DH=64.
// M = T*B = 8192 rows for all GEMMs, K = N = 1024.

typedef __bf16 bf16x8 __attribute__((ext_vector_type(8)));
typedef float f32x4 __attribute__((ext_vector_type(4)));

__device__ __forceinline__ unsigned short f2bf(float f) {
  unsigned int u = __builtin_bit_cast(unsigned int, f);
  u += 0x7FFFu + ((u >> 16) & 1u);   // RNE; inputs are finite
  return (unsigned short)(u >> 16);
}

#define BMT 128
#define BNT 128
#define BKT 64
#define LDT 72   // padded LDS row stride (elements): 144B -> 2-way (free) conflicts

// C = A @ (bscale * B).  A: M x K (fp32 or bf16, row-major). B: K x N fp32 row-major.
// Output: bf16 (ushort) or fp32 per template flag.
template<bool A_BF16, bool OUT_BF16>
__global__ __launch_bounds__(256)
void gemm_conv(const void* __restrict__ Ap, const float* __restrict__ Bp,
               void* __restrict__ Cp, int M, int N, int K, float bscale)
{
  __shared__ __align__(16) unsigned short As[BMT][LDT];
  __shared__ __align__(16) unsigned short Bs[BNT][LDT];  // transposed: [n][k]
  const int tid  = threadIdx.x;
  const int lane = tid & 63;
  const int wid  = tid >> 6;
  const int wr   = wid >> 1;
  const int wc   = wid & 1;
  const int l15  = lane & 15;
  const int l4   = lane >> 4;
  const int bm = blockIdx.x, bn = blockIdx.y;

  f32x4 acc[4][4];
#pragma unroll
  for (int m = 0; m < 4; ++m)
#pragma unroll
    for (int n = 0; n < 4; ++n)
      acc[m][n] = (f32x4){0.f, 0.f, 0.f, 0.f};

  for (int kt = 0; kt < K; kt += BKT) {
    if (kt) __syncthreads();  // previous compute must finish before re-staging
    // ---- stage A tile (128 x 64) as bf16 into As ----
    if constexpr (A_BF16) {
      const unsigned short* A = (const unsigned short*)Ap;
#pragma unroll
      for (int i = 0; i < 4; ++i) {
        int e = (i * 256 + tid) * 8;
        int r = e >> 6, c = e & 63;
        uint4 v = *(const uint4*)(A + (size_t)(bm * BMT + r) * K + kt + c);
        *(uint4*)(&As[r][c]) = v;
      }
    } else {
      const float* A = (const float*)Ap;
#pragma unroll
      for (int i = 0; i < 8; ++i) {
        int e = (i * 256 + tid) * 4;
        int r = e >> 6, c = e & 63;
        float4 v = *(const float4*)(A + (size_t)(bm * BMT + r) * K + kt + c);
        ushort4 h;
        h.x = f2bf(v.x); h.y = f2bf(v.y); h.z = f2bf(v.z); h.w = f2bf(v.w);
        *(ushort4*)(&As[r][c]) = h;
      }
    }
    // ---- stage B tile (64 x 128) transposed into Bs[n][k], scaled ----
    {
#pragma unroll
      for (int i = 0; i < 8; ++i) {
        int e = (i * 256 + tid) * 4;
        int r = e >> 7, c = e & 127;
        float4 v = *(const float4*)(Bp + (size_t)(kt + r) * N + bn * BNT + c);
        Bs[c + 0][r] = f2bf(v.x * bscale);
        Bs[c + 1][r] = f2bf(v.y * bscale);
        Bs[c + 2][r] = f2bf(v.z * bscale);
        Bs[c + 3][r] = f2bf(v.w * bscale);
      }
    }
    __syncthreads();
    // ---- MFMA inner loop ----
#pragma unroll
    for (int kk = 0; kk < 2; ++kk) {
      bf16x8 af[4], bfr[4];
#pragma unroll
      for (int m = 0; m < 4; ++m)
        af[m] = *(const bf16x8*)(&As[wr * 64 + m * 16 + l15][kk * 32 + l4 * 8]);
#pragma unroll
      for (int n = 0; n < 4; ++n)
        bfr[n] = *(const bf16x8*)(&Bs[wc * 64 + n * 16 + l15][kk * 32 + l4 * 8]);
#pragma unroll
      for (int m = 0; m < 4; ++m)
#pragma unroll
        for (int n = 0; n < 4; ++n)
          acc[m][n] = __builtin_amdgcn_mfma_f32_16x16x32_bf16(af[m], bfr[n], acc[m][n], 0, 0, 0);
    }
  }

  // ---- epilogue: C/D layout row=(l>>4)*4+r, col=l&15 (measured m89/m91) ----
#pragma unroll
  for (int m = 0; m < 4; ++m)
#pragma unroll
    for (int n = 0; n < 4; ++n)
#pragma unroll
      for (int r = 0; r < 4; ++r) {
        size_t row = (size_t)(bm * BMT + wr * 64 + m * 16 + l4 * 4 + r);
        size_t col = (size_t)(bn * BNT + wc * 64 + n * 16 + l15);
        if constexpr (OUT_BF16)
          ((unsigned short*)Cp)[row * N + col] = f2bf(acc[m][n][r]);
        else
          ((float*)Cp)[row * N + col] = acc[m][n][r];
      }
}

// Causal flash attention. hq/hk/hv: (T,B,H,DH) bf16 = rows of 8192 elements,
// head offset b*1024 + h*64. One block = one (b,h) x 64 Q-rows; 4 waves x 16 rows.
__global__ __launch_bounds__(256)
void flash_attn(const unsigned short* __restrict__ hq,
                const unsigned short* __restrict__ hk,
                const unsigned short* __restrict__ hv,
                unsigned short* __restrict__ vec)
{
  __shared__ __align__(16) unsigned short Pbuf[4][16][40];  // per-wave, padded
  const int tid  = threadIdx.x;
  const int lane = tid & 63;
  const int wid  = tid >> 6;
  const int l15  = lane & 15;
  const int l4   = lane >> 4;
  const int qb = blockIdx.x;       // 0..15
  const int bh = blockIdx.y;       // 0..127
  const size_t bho = (size_t)(bh >> 4) * 1024 + (size_t)(bh & 15) * 64;
  const int t0 = qb * 64 + wid * 16;

  // Q A-fragments (scale already folded into Wq)
  bf16x8 qf[2];
#pragma unroll
  for (int ks = 0; ks < 2; ++ks)
    qf[ks] = *(const bf16x8*)(hq + (size_t)(t0 + l15) * 8192 + bho + ks * 32 + l4 * 8);

  f32x4 of[4];
#pragma unroll
  for (int n = 0; n < 4; ++n) of[n] = (f32x4){0.f, 0.f, 0.f, 0.f};
  float mrun[4], lrun[4];
#pragma unroll
  for (int r = 0; r < 4; ++r) { mrun[r] = -3.0e38f; lrun[r] = 0.f; }

  const __bf16* hvb = (const __bf16*)hv;
  const int nch = (t0 + 15) / 32 + 1;

  for (int c = 0; c < nch; ++c) {
    const int kv0 = c * 32;
    // K as B-fragments of K^T (lane: col=kv=l15, k=d contiguous)
    bf16x8 kf[2][2];
#pragma unroll
    for (int n = 0; n < 2; ++n)
#pragma unroll
      for (int ks = 0; ks < 2; ++ks)
        kf[n][ks] = *(const bf16x8*)(hk + (size_t)(kv0 + n * 16 + l15) * 8192 + bho + ks * 32 + l4 * 8);

    f32x4 s[2];
    s[0] = (f32x4){0.f, 0.f, 0.f, 0.f};
    s[1] = (f32x4){0.f, 0.f, 0.f, 0.f};
#pragma unroll
    for (int ks = 0; ks < 2; ++ks) {
      s[0] = __builtin_amdgcn_mfma_f32_16x16x32_bf16(qf[ks], kf[0][ks], s[0], 0, 0, 0);
      s[1] = __builtin_amdgcn_mfma_f32_16x16x32_bf16(qf[ks], kf[1][ks], s[1], 0, 0, 0);
    }

    // causal mask in C layout: i = t0 + l4*4 + r, j = kv0 + n*16 + l15
    float sc[2][4];
#pragma unroll
    for (int n = 0; n < 2; ++n)
#pragma unroll
      for (int r = 0; r < 4; ++r) {
        int i = t0 + l4 * 4 + r;
        int j = kv0 + n * 16 + l15;
        sc[n][r] = (j > i) ? -1.0e30f : s[n][r];
      }

    // online softmax (row spread over 16 lanes: shfl_xor 1,2,4,8)
    float alpha[4];
#pragma unroll
    for (int r = 0; r < 4; ++r) {
      float pm = fmaxf(sc[0][r], sc[1][r]);
      pm = fmaxf(pm, __shfl_xor(pm, 1));
      pm = fmaxf(pm, __shfl_xor(pm, 2));
      pm = fmaxf(pm, __shfl_xor(pm, 4));
      pm = fmaxf(pm, __shfl_xor(pm, 8));
      float nm = fmaxf(mrun[r], pm);
      alpha[r] = __expf(mrun[r] - nm);
      mrun[r] = nm;
    }
    float p0[4], p1[4];
#pragma unroll
    for (int r = 0; r < 4; ++r) {
      p0[r] = __expf(sc[0][r] - mrun[r]);
      p1[r] = __expf(sc[1][r] - mrun[r]);
      float ps = p0[r] + p1[r];
      ps += __shfl_xor(ps, 1);
      ps += __shfl_xor(ps, 2);
      ps += __shfl_xor(ps, 4);
      ps += __shfl_xor(ps, 8);
      lrun[r] = lrun[r] * alpha[r] + ps;
    }
#pragma unroll
    for (int n = 0; n < 4; ++n)
#pragma unroll
      for (int r = 0; r < 4; ++r)
        of[n][r] *= alpha[r];

    // P: C-layout -> LDS -> A-layout (per-wave private buffer)
#pragma unroll
    for (int r = 0; r < 4; ++r) {
      Pbuf[wid][l4 * 4 + r][l15]      = f2bf(p0[r]);
      Pbuf[wid][l4 * 4 + r][16 + l15] = f2bf(p1[r]);
    }
    bf16x8 pf = *(const bf16x8*)(&Pbuf[wid][l15][l4 * 8]);

    // PV: B = V (lane: col=d=l15, k=kv contiguous -> strided scalar loads)
#pragma unroll
    for (int n = 0; n < 4; ++n) {
      bf16x8 vf;
#pragma unroll
      for (int j = 0; j < 8; ++j)
        vf[j] = hvb[(size_t)(kv0 + l4 * 8 + j) * 8192 + bho + n * 16 + l15];
      of[n] = __builtin_amdgcn_mfma_f32_16x16x32_bf16(pf, vf, of[n], 0, 0, 0);
    }
  }

  // normalize and store vec (bf16)
#pragma unroll
  for (int n = 0; n < 4; ++n)
#pragma unroll
    for (int r = 0; r < 4; ++r) {
      int t = t0 + l4 * 4 + r;
      float v = of[n][r] / lrun[r];
      vec[(size_t)t * 8192 + bho + n * 16 + l15] = f2bf(v);
    }
}

// In-place LayerNorm over rows of 1024 fp32. One block per row.
__global__ __launch_bounds__(256)
void ln_inplace(float* __restrict__ x, const float* __restrict__ gamma,
                const float* __restrict__ beta)
{
  __shared__ float red[2][4];
  const int tid  = threadIdx.x;
  const int lane = tid & 63;
  const int wid  = tid >> 6;
  const size_t row = blockIdx.x;
  float4 v = *(const float4*)(x + row * 1024 + tid * 4);
  float s = v.x + v.y + v.z + v.w;
  float q = v.x * v.x + v.y * v.y + v.z * v.z + v.w * v.w;
#pragma unroll
  for (int m = 1; m <= 32; m <<= 1) {
    s += __shfl_xor(s, m);
    q += __shfl_xor(q, m);
  }
  if (lane == 0) { red[0][wid] = s; red[1][wid] = q; }
  __syncthreads();
  float ts = red[0][0] + red[0][1] + red[0][2] + red[0][3];
  float tq = red[1][0] + red[1][1] + red[1][2] + red[1][3];
  float mu = ts * (1.0f / 1024.0f);
  float var = tq * (1.0f / 1024.0f) - mu * mu;
  float rs = rsqrtf(var + 1e-5f);
  float4 g  = *(const float4*)(gamma + tid * 4);
  float4 bt = *(const float4*)(beta + tid * 4);
  v.x = (v.x - mu) * rs * g.x + bt.x;
  v.y = (v.y - mu) * rs * g.y + bt.y;
  v.z = (v.z - mu) * rs * g.z + bt.z;
  v.w = (v.w - mu) * rs * g.w + bt.w;
  *(float4*)(x + row * 1024 + tid * 4) = v;
}

extern "C" void kernel_launch(void* const* d_in, const int* in_sizes, int n_in,
                              void* d_out, int out_size, void* d_ws, size_t ws_size,
                              hipStream_t stream) {
  const float* q     = (const float*)d_in[0];
  const float* k     = (const float*)d_in[1];
  const float* v     = (const float*)d_in[2];
  // d_in[3] = attn_mask (causal triu) -- computed analytically in-kernel
  const float* Wq    = (const float*)d_in[4];
  const float* Wk    = (const float*)d_in[5];
  const float* Wv    = (const float*)d_in[6];
  const float* Wo    = (const float*)d_in[7];
  const float* gamma = (const float*)d_in[8];
  const float* beta  = (const float*)d_in[9];

  unsigned short* hq  = (unsigned short*)d_ws;          // 8192x1024 bf16
  unsigned short* hk  = hq + (size_t)8192 * 1024;
  unsigned short* hv  = hk + (size_t)8192 * 1024;
  unsigned short* vec = hv + (size_t)8192 * 1024;       // 8192x1024 bf16
  float* out = (float*)d_out;

  dim3 gg(64, 8);          // M/128 x N/128
  dim3 bb(256);
  // projections; fold score scale 1/sqrt(64)=0.125 into Wq (exact: power of 2)
  gemm_conv<false, true><<<gg, bb, 0, stream>>>(q, Wq, hq, 8192, 1024, 1024, 0.125f);
  gemm_conv<false, true><<<gg, bb, 0, stream>>>(k, Wk, hk, 8192, 1024, 1024, 1.0f);
  gemm_conv<false, true><<<gg, bb, 0, stream>>>(v, Wv, hv, 8192, 1024, 1024, 1.0f);
  // causal flash attention
  flash_attn<<<dim3(16, 128), bb, 0, stream>>>(hq, hk, hv, vec);
  // output projection -> d_out (fp32), then in-place LayerNorm
  gemm_conv<true, false><<<gg, bb, 0, stream>>>(vec, Wo, out, 8192, 1024, 1024, 1.0f);
  ln_inplace<<<8192, bb, 0, stream>>>(out, gamma, beta);
}

// Round 2
// 413.488 us; speedup vs baseline: 1.4867x; 1.4867x over previous
//
#include <hip/hip_runtime.h>
#include <hip/hip_bf16.h>

// Shapes fixed by the reference: T=1024, B=8, D=1024, H=16, DH=64. M=T*B=8192.
// Intermediate layouts: hq,hk = (B,H,T,DH) bf16; hvt = (B,H,DH,T) bf16 (V^T);
// vec = row-major (M,1024) bf16 with m = t*8+b.

typedef __bf16 bf16x8 __attribute__((ext_vector_type(8)));
typedef float f32x4 __attribute__((ext_vector_type(4)));
typedef unsigned short ushort8_t __attribute__((ext_vector_type(8)));

__device__ __forceinline__ unsigned short f2bf(float f) {
  unsigned int u = __builtin_bit_cast(unsigned int, f);
  u += 0x7FFFu + ((u >> 16) & 1u);   // RNE; finite inputs
  return (unsigned short)(u >> 16);
}

__device__ __forceinline__ void gl2lds16(const unsigned short* g, unsigned short* l) {
  __builtin_amdgcn_global_load_lds(
      (const __attribute__((address_space(1))) void*)g,
      (__attribute__((address_space(3))) void*)l, 16, 0, 0);
}

// ---------------- bf16 -> bf16 GEMM, m97 structure ----------------
// A: [8192][1024] bf16 row-major. Bt: [1024][1024] bf16 = W^T ([n][k]).
// EPI 0: bf16 out at ((b*16+h)*1024+t)*64+dh   (B,H,T,DH)
// EPI 1: bf16 out at ((b*16+h)*64+dh)*1024+t   (B,H,DH,T)  [V^T]
// EPI 2: fp32 out row-major [8192][1024]
template<int EPI>
__global__ __launch_bounds__(256)
void gemm_bf16(const unsigned short* __restrict__ A,
               const unsigned short* __restrict__ Bt,
               void* __restrict__ C)
{
  __shared__ __align__(16) unsigned short As[128 * 64];
  __shared__ __align__(16) unsigned short Bs[128 * 64];
  const int tid = threadIdx.x;
  const int lane = tid & 63, wid = tid >> 6;
  const int wr = wid >> 1, wc = wid & 1;
  const int l15 = lane & 15, l4 = lane >> 4;
  const int bm = blockIdx.x, bn = blockIdx.y;

  f32x4 acc[4][4];
#pragma unroll
  for (int m = 0; m < 4; ++m)
#pragma unroll
    for (int n = 0; n < 4; ++n)
      acc[m][n] = (f32x4){0.f, 0.f, 0.f, 0.f};

  // staging: thread loads 16B; row = i*32 + tid>>3, col = (tid&7)*8
  const unsigned short* ga = A  + (size_t)bm * 128 * 1024 + (tid >> 3) * 1024 + (tid & 7) * 8;
  const unsigned short* gb = Bt + (size_t)bn * 128 * 1024 + (tid >> 3) * 1024 + (tid & 7) * 8;
  unsigned short* la = As + wid * 512;   // wave-uniform LDS base; HW adds lane*16B
  unsigned short* lb = Bs + wid * 512;

  for (int kt = 0; kt < 1024; kt += 64) {
    if (kt) __syncthreads();
#pragma unroll
    for (int i = 0; i < 4; ++i) {
      gl2lds16(ga + i * 32 * 1024 + kt, la + i * 2048);
      gl2lds16(gb + i * 32 * 1024 + kt, lb + i * 2048);
    }
    __syncthreads();   // drains vmcnt (global_load_lds) before use
#pragma unroll
    for (int kk = 0; kk < 2; ++kk) {
      bf16x8 af[4], bfr[4];
#pragma unroll
      for (int m = 0; m < 4; ++m)
        af[m] = *(const bf16x8*)(As + (wr * 64 + m * 16 + l15) * 64 + kk * 32 + l4 * 8);
#pragma unroll
      for (int n = 0; n < 4; ++n)
        bfr[n] = *(const bf16x8*)(Bs + (wc * 64 + n * 16 + l15) * 64 + kk * 32 + l4 * 8);
#pragma unroll
      for (int m = 0; m < 4; ++m)
#pragma unroll
        for (int n = 0; n < 4; ++n)
          acc[m][n] = __builtin_amdgcn_mfma_f32_16x16x32_bf16(af[m], bfr[n], acc[m][n], 0, 0, 0);
    }
  }

  // C/D layout: row = (l>>4)*4 + r, col = l&15 (measured m89/m91)
#pragma unroll
  for (int m = 0; m < 4; ++m)
#pragma unroll
    for (int n = 0; n < 4; ++n)
#pragma unroll
      for (int r = 0; r < 4; ++r) {
        int row = bm * 128 + wr * 64 + m * 16 + l4 * 4 + r;   // m = t*8+b
        int col = bn * 128 + wc * 64 + n * 16 + l15;           // h*64+dh
        float v = acc[m][n][r];
        if constexpr (EPI == 2) {
          ((float*)C)[(size_t)row * 1024 + col] = v;
        } else {
          int t = row >> 3, b = row & 7;
          int h = col >> 6, dh = col & 63;
          size_t base = ((size_t)(b * 16 + h)) << 16;   // *65536
          size_t idx = (EPI == 0) ? base + (size_t)t * 64 + dh
                                  : base + (size_t)dh * 1024 + t;
          ((unsigned short*)C)[idx] = f2bf(v);
        }
      }
}

// ---------------- fp32 -> bf16 convert (vectorized) ----------------
__global__ __launch_bounds__(256)
void conv_bf16(const float* __restrict__ in, unsigned short* __restrict__ out)
{
  size_t i = ((size_t)blockIdx.x * 256 + threadIdx.x) * 8;
  float4 a = *(const float4*)(in + i);
  float4 b = *(const float4*)(in + i + 4);
  ushort8_t o;
  o[0] = f2bf(a.x); o[1] = f2bf(a.y); o[2] = f2bf(a.z); o[3] = f2bf(a.w);
  o[4] = f2bf(b.x); o[5] = f2bf(b.y); o[6] = f2bf(b.z); o[7] = f2bf(b.w);
  *(ushort8_t*)(out + i) = o;
}

// ---------------- weight transpose+convert: W[k][n] fp32 -> Wt[n][k] bf16 ----
__global__ __launch_bounds__(256)
void wconv(const float* __restrict__ W, unsigned short* __restrict__ Wt, float scale)
{
  int id = blockIdx.x * 256 + threadIdx.x;   // 131072 threads
  int n = id & 1023;
  int k0 = (id >> 10) << 3;
  ushort8_t o;
#pragma unroll
  for (int j = 0; j < 8; ++j)
    o[j] = f2bf(W[(size_t)(k0 + j) * 1024 + n] * scale);
  *(ushort8_t*)(Wt + (size_t)n * 1024 + k0) = o;
}

// ---------------- causal flash attention ----------------
// Block = (qb, bh): 64 Q-rows of head bh; 4 waves x 16 rows. KV chunk = 64.
__global__ __launch_bounds__(256)
void flash_attn(const unsigned short* __restrict__ hq,
                const unsigned short* __restrict__ hk,
                const unsigned short* __restrict__ hvt,
                unsigned short* __restrict__ vec)
{
  __shared__ __align__(16) unsigned short Pbuf[4][16][72];  // stride 144B: b128-aligned, 2-way-free banks
  const int tid = threadIdx.x;
  const int lane = tid & 63, wid = tid >> 6;
  const int l15 = lane & 15, l4 = lane >> 4;
  const int qb = blockIdx.x, bh = blockIdx.y;
  const int b = bh >> 4, h = bh & 15;
  const size_t base = (size_t)bh << 16;       // *65536 elems per head
  const int t0 = qb * 64 + wid * 16;

  bf16x8 qf[2];
#pragma unroll
  for (int ks = 0; ks < 2; ++ks)
    qf[ks] = *(const bf16x8*)(hq + base + (size_t)(t0 + l15) * 64 + ks * 32 + l4 * 8);

  f32x4 of[4];
#pragma unroll
  for (int n = 0; n < 4; ++n) of[n] = (f32x4){0.f, 0.f, 0.f, 0.f};
  float mrun[4], lrun[4];
#pragma unroll
  for (int r = 0; r < 4; ++r) { mrun[r] = -3.0e38f; lrun[r] = 0.f; }

  for (int c = 0; c <= qb; ++c) {
    const int kv0 = c * 64;
    const bool maskc = (c == qb);

    // QK^T: A=Q, B=K^T fragments (contiguous 16B loads)
    f32x4 s[4];
#pragma unroll
    for (int n = 0; n < 4; ++n) s[n] = (f32x4){0.f, 0.f, 0.f, 0.f};
#pragma unroll
    for (int n = 0; n < 4; ++n)
#pragma unroll
      for (int ks = 0; ks < 2; ++ks) {
        bf16x8 kf = *(const bf16x8*)(hk + base + (size_t)(kv0 + n * 16 + l15) * 64 + ks * 32 + l4 * 8);
        s[n] = __builtin_amdgcn_mfma_f32_16x16x32_bf16(qf[ks], kf, s[n], 0, 0, 0);
      }

    float sc[4][4];
#pragma unroll
    for (int n = 0; n < 4; ++n)
#pragma unroll
      for (int r = 0; r < 4; ++r) sc[n][r] = s[n][r];
    if (maskc) {
#pragma unroll
      for (int n = 0; n < 4; ++n)
#pragma unroll
        for (int r = 0; r < 4; ++r)
          if (kv0 + n * 16 + l15 > t0 + l4 * 4 + r) sc[n][r] = -1.0e30f;
    }

    // online softmax; row lives on 16 lanes (l15), reduce via xor 1,2,4,8
    float alpha[4];
#pragma unroll
    for (int r = 0; r < 4; ++r) {
      float pm = fmaxf(fmaxf(sc[0][r], sc[1][r]), fmaxf(sc[2][r], sc[3][r]));
      pm = fmaxf(pm, __shfl_xor(pm, 1));
      pm = fmaxf(pm, __shfl_xor(pm, 2));
      pm = fmaxf(pm, __shfl_xor(pm, 4));
      pm = fmaxf(pm, __shfl_xor(pm, 8));
      float nm = fmaxf(mrun[r], pm);
      alpha[r] = __expf(mrun[r] - nm);
      mrun[r] = nm;
    }
#pragma unroll
    for (int r = 0; r < 4; ++r) {
      float ps = 0.f;
#pragma unroll
      for (int n = 0; n < 4; ++n) {
        sc[n][r] = __expf(sc[n][r] - mrun[r]);
        ps += sc[n][r];
      }
      ps += __shfl_xor(ps, 1);
      ps += __shfl_xor(ps, 2);
      ps += __shfl_xor(ps, 4);
      ps += __shfl_xor(ps, 8);
      lrun[r] = lrun[r] * alpha[r] + ps;
    }
#pragma unroll
    for (int n = 0; n < 4; ++n)
#pragma unroll
      for (int r = 0; r < 4; ++r) of[n][r] *= alpha[r];

    // P: C-layout -> per-wave LDS -> A-layout fragments
#pragma unroll
    for (int n = 0; n < 4; ++n)
#pragma unroll
      for (int r = 0; r < 4; ++r)
        Pbuf[wid][l4 * 4 + r][n * 16 + l15] = f2bf(sc[n][r]);
    bf16x8 pf0 = *(const bf16x8*)(&Pbuf[wid][l15][l4 * 8]);
    bf16x8 pf1 = *(const bf16x8*)(&Pbuf[wid][l15][32 + l4 * 8]);

    // PV: B = V^T rows (contiguous 16B loads along kv)
#pragma unroll
    for (int n = 0; n < 4; ++n) {
      bf16x8 vf0 = *(const bf16x8*)(hvt + base + (size_t)(n * 16 + l15) * 1024 + kv0 + l4 * 8);
      bf16x8 vf1 = *(const bf16x8*)(hvt + base + (size_t)(n * 16 + l15) * 1024 + kv0 + 32 + l4 * 8);
      of[n] = __builtin_amdgcn_mfma_f32_16x16x32_bf16(pf0, vf0, of[n], 0, 0, 0);
      of[n] = __builtin_amdgcn_mfma_f32_16x16x32_bf16(pf1, vf1, of[n], 0, 0, 0);
    }
  }

  // vec row-major: m = t*8+b, col = h*64+dh
#pragma unroll
  for (int n = 0; n < 4; ++n)
#pragma unroll
    for (int r = 0; r < 4; ++r) {
      int t = t0 + l4 * 4 + r;
      vec[((size_t)t * 8 + b) * 1024 + h * 64 + n * 16 + l15] = f2bf(of[n][r] / lrun[r]);
    }
}

// ---------------- in-place LayerNorm over rows of 1024 fp32 ----------------
__global__ __launch_bounds__(256)
void ln_inplace(float* __restrict__ x, const float* __restrict__ gamma,
                const float* __restrict__ beta)
{
  __shared__ float red[2][4];
  const int tid = threadIdx.x;
  const int lane = tid & 63, wid = tid >> 6;
  const size_t row = blockIdx.x;
  float4 v = *(const float4*)(x + row * 1024 + tid * 4);
  float s = v.x + v.y + v.z + v.w;
  float q = v.x * v.x + v.y * v.y + v.z * v.z + v.w * v.w;
#pragma unroll
  for (int m = 1; m <= 32; m <<= 1) {
    s += __shfl_xor(s, m);
    q += __shfl_xor(q, m);
  }
  if (lane == 0) { red[0][wid] = s; red[1][wid] = q; }
  __syncthreads();
  float ts = red[0][0] + red[0][1] + red[0][2] + red[0][3];
  float tq = red[1][0] + red[1][1] + red[1][2] + red[1][3];
  float mu = ts * (1.0f / 1024.0f);
  float var = tq * (1.0f / 1024.0f) - mu * mu;
  float rs = rsqrtf(var + 1e-5f);
  float4 g  = *(const float4*)(gamma + tid * 4);
  float4 bt = *(const float4*)(beta + tid * 4);
  v.x = (v.x - mu) * rs * g.x + bt.x;
  v.y = (v.y - mu) * rs * g.y + bt.y;
  v.z = (v.z - mu) * rs * g.z + bt.z;
  v.w = (v.w - mu) * rs * g.w + bt.w;
  *(float4*)(x + row * 1024 + tid * 4) = v;
}

extern "C" void kernel_launch(void* const* d_in, const int* in_sizes, int n_in,
                              void* d_out, int out_size, void* d_ws, size_t ws_size,
                              hipStream_t stream) {
  const float* q     = (const float*)d_in[0];
  const float* k     = (const float*)d_in[1];
  const float* v     = (const float*)d_in[2];
  // d_in[3] = attn_mask (causal) -- analytic in-kernel
  const float* Wq    = (const float*)d_in[4];
  const float* Wk    = (const float*)d_in[5];
  const float* Wv    = (const float*)d_in[6];
  const float* Wo    = (const float*)d_in[7];
  const float* gamma = (const float*)d_in[8];
  const float* beta  = (const float*)d_in[9];

  unsigned short* ws = (unsigned short*)d_ws;
  const size_t MSZ = (size_t)8192 * 1024;
  unsigned short* hq  = ws;                 // (B,H,T,DH)
  unsigned short* hk  = ws + MSZ;           // (B,H,T,DH)
  unsigned short* hvt = ws + 2 * MSZ;       // (B,H,DH,T)
  unsigned short* tmp = ws + 3 * MSZ;       // conv buffer, then vec
  unsigned short* WqT = ws + 4 * MSZ;       // 4x [1024][1024] bf16
  unsigned short* WkT = WqT + 1048576;
  unsigned short* WvT = WqT + 2097152;
  unsigned short* WoT = WqT + 3145728;
  float* out = (float*)d_out;

  dim3 bb(256);
  dim3 gg(64, 8);
  // weights -> bf16 [n][k]; fold 1/sqrt(DH)=0.125 into Wq (exact pow2)
  wconv<<<512, bb, 0, stream>>>(Wq, WqT, 0.125f);
  wconv<<<512, bb, 0, stream>>>(Wk, WkT, 1.0f);
  wconv<<<512, bb, 0, stream>>>(Wv, WvT, 1.0f);
  wconv<<<512, bb, 0, stream>>>(Wo, WoT, 1.0f);

  conv_bf16<<<4096, bb, 0, stream>>>(v, tmp);
  gemm_bf16<1><<<gg, bb, 0, stream>>>(tmp, WvT, hvt);
  conv_bf16<<<4096, bb, 0, stream>>>(q, tmp);
  gemm_bf16<0><<<gg, bb, 0, stream>>>(tmp, WqT, hq);
  conv_bf16<<<4096, bb, 0, stream>>>(k, tmp);
  gemm_bf16<0><<<gg, bb, 0, stream>>>(tmp, WkT, hk);

  flash_attn<<<dim3(16, 128), bb, 0, stream>>>(hq, hk, hvt, tmp);  // vec = tmp

  gemm_bf16<2><<<gg, bb, 0, stream>>>(tmp, WoT, out);
  ln_inplace<<<8192, bb, 0, stream>>>(out, gamma, beta);
}

// Round 4
// 288.354 us; speedup vs baseline: 2.1319x; 1.4340x over previous
//
#include <hip/hip_runtime.h>
#include <hip/hip_bf16.h>

// Shapes fixed by the reference: T=1024, B=8, D=1024, H=16, DH=64. M=T*B=8192.
// Intermediate layouts: hq,hk = (B,H,T,DH) bf16; hvt = (B,H,DH,T) bf16 (V^T);
// vec = row-major (M,1024) bf16 with m = t*8+b.
// Scores are produced in log2-domain: 0.125*log2(e) folded into Wq.

typedef __bf16 bf16x8 __attribute__((ext_vector_type(8)));
typedef float f32x4 __attribute__((ext_vector_type(4)));
typedef float f32x16 __attribute__((ext_vector_type(16)));
typedef unsigned short ushort8_t __attribute__((ext_vector_type(8)));

__device__ __forceinline__ unsigned short f2bf(float f) {
  unsigned int u = __builtin_bit_cast(unsigned int, f);
  u += 0x7FFFu + ((u >> 16) & 1u);   // RNE; finite inputs
  return (unsigned short)(u >> 16);
}

__device__ __forceinline__ unsigned int cvt_pk_bf16(float lo, float hi) {
  unsigned int r;
  asm("v_cvt_pk_bf16_f32 %0, %1, %2" : "=v"(r) : "v"(lo), "v"(hi));
  return r;
}

__device__ __forceinline__ void gl2lds16(const unsigned short* g, unsigned short* l) {
  __builtin_amdgcn_global_load_lds(
      (const __attribute__((address_space(1))) void*)g,
      (__attribute__((address_space(3))) void*)l, 16, 0, 0);
}

// ---------------- bf16 -> bf16 GEMM, m97 structure ----------------
// A: [8192][1024] bf16 row-major. Bt: [1024][1024] bf16 = W^T ([n][k]).
// EPI 0: bf16 out at ((b*16+h)*1024+t)*64+dh   (B,H,T,DH)
// EPI 1: bf16 out at ((b*16+h)*64+dh)*1024+t   (B,H,DH,T)  [V^T]
// EPI 2: fp32 out row-major [8192][1024]
template<int EPI>
__global__ __launch_bounds__(256)
void gemm_bf16(const unsigned short* __restrict__ A,
               const unsigned short* __restrict__ Bt,
               void* __restrict__ C)
{
  __shared__ __align__(16) unsigned short As[128 * 64];
  __shared__ __align__(16) unsigned short Bs[128 * 64];
  const int tid = threadIdx.x;
  const int lane = tid & 63, wid = tid >> 6;
  const int wr = wid >> 1, wc = wid & 1;
  const int l15 = lane & 15, l4 = lane >> 4;
  const int bm = blockIdx.x, bn = blockIdx.y;

  f32x4 acc[4][4];
#pragma unroll
  for (int m = 0; m < 4; ++m)
#pragma unroll
    for (int n = 0; n < 4; ++n)
      acc[m][n] = (f32x4){0.f, 0.f, 0.f, 0.f};

  const unsigned short* ga = A  + (size_t)bm * 128 * 1024 + (tid >> 3) * 1024 + (tid & 7) * 8;
  const unsigned short* gb = Bt + (size_t)bn * 128 * 1024 + (tid >> 3) * 1024 + (tid & 7) * 8;
  unsigned short* la = As + wid * 512;   // wave-uniform LDS base; HW adds lane*16B
  unsigned short* lb = Bs + wid * 512;

  for (int kt = 0; kt < 1024; kt += 64) {
    if (kt) __syncthreads();
#pragma unroll
    for (int i = 0; i < 4; ++i) {
      gl2lds16(ga + i * 32 * 1024 + kt, la + i * 2048);
      gl2lds16(gb + i * 32 * 1024 + kt, lb + i * 2048);
    }
    __syncthreads();
#pragma unroll
    for (int kk = 0; kk < 2; ++kk) {
      bf16x8 af[4], bfr[4];
#pragma unroll
      for (int m = 0; m < 4; ++m)
        af[m] = *(const bf16x8*)(As + (wr * 64 + m * 16 + l15) * 64 + kk * 32 + l4 * 8);
#pragma unroll
      for (int n = 0; n < 4; ++n)
        bfr[n] = *(const bf16x8*)(Bs + (wc * 64 + n * 16 + l15) * 64 + kk * 32 + l4 * 8);
#pragma unroll
      for (int m = 0; m < 4; ++m)
#pragma unroll
        for (int n = 0; n < 4; ++n)
          acc[m][n] = __builtin_amdgcn_mfma_f32_16x16x32_bf16(af[m], bfr[n], acc[m][n], 0, 0, 0);
    }
  }

#pragma unroll
  for (int m = 0; m < 4; ++m)
#pragma unroll
    for (int n = 0; n < 4; ++n)
#pragma unroll
      for (int r = 0; r < 4; ++r) {
        int row = bm * 128 + wr * 64 + m * 16 + l4 * 4 + r;   // m = t*8+b
        int col = bn * 128 + wc * 64 + n * 16 + l15;           // h*64+dh
        float v = acc[m][n][r];
        if constexpr (EPI == 2) {
          ((float*)C)[(size_t)row * 1024 + col] = v;
        } else {
          int t = row >> 3, b = row & 7;
          int h = col >> 6, dh = col & 63;
          size_t base = ((size_t)(b * 16 + h)) << 16;
          size_t idx = (EPI == 0) ? base + (size_t)t * 64 + dh
                                  : base + (size_t)dh * 1024 + t;
          ((unsigned short*)C)[idx] = f2bf(v);
        }
      }
}

// ---------------- fp32 -> bf16 convert (vectorized) ----------------
__global__ __launch_bounds__(256)
void conv_bf16(const float* __restrict__ in, unsigned short* __restrict__ out)
{
  size_t i = ((size_t)blockIdx.x * 256 + threadIdx.x) * 8;
  float4 a = *(const float4*)(in + i);
  float4 b = *(const float4*)(in + i + 4);
  ushort8_t o;
  o[0] = f2bf(a.x); o[1] = f2bf(a.y); o[2] = f2bf(a.z); o[3] = f2bf(a.w);
  o[4] = f2bf(b.x); o[5] = f2bf(b.y); o[6] = f2bf(b.z); o[7] = f2bf(b.w);
  *(ushort8_t*)(out + i) = o;
}

// ---------------- weight transpose+convert: W[k][n] fp32 -> Wt[n][k] bf16 ----
__global__ __launch_bounds__(256)
void wconv(const float* __restrict__ W, unsigned short* __restrict__ Wt, float scale)
{
  int id = blockIdx.x * 256 + threadIdx.x;
  int n = id & 1023;
  int k0 = (id >> 10) << 3;
  ushort8_t o;
#pragma unroll
  for (int j = 0; j < 8; ++j)
    o[j] = f2bf(W[(size_t)(k0 + j) * 1024 + n] * scale);
  *(ushort8_t*)(Wt + (size_t)n * 1024 + k0) = o;
}

// ---------------- causal flash attention (swapped 32x32 MFMA, no LDS) -------
// 1024 blocks x 256 threads, 4 independent waves/block, 32 q-rows per wave.
// S^T = K*Q^T  -> lane holds 32 scores of q-row (lane&31)   [C: col=lane&31]
// O^T = V^T*P^T -> lane holds O columns for same q-row      [alpha lane-local]
// PV uses k-slot permutation pi(s2,h,j)=(j&3)+8*(2*s2+(j>>2))+4h applied to
// BOTH operands: B-fragment = lane's own p[8*s2+j] in order (no cross-lane),
// A-fragment = V^T at kv = kvb+16*s2+4h+{0..3} and +8 (two 8B loads).
__global__ __launch_bounds__(256)
void flash_attn(const unsigned short* __restrict__ hq,
                const unsigned short* __restrict__ hk,
                const unsigned short* __restrict__ hvt,
                unsigned short* __restrict__ vec)
{
  const int tid = threadIdx.x;
  const int lane = tid & 63, wid = tid >> 6;
  const int l31 = lane & 31, h = lane >> 5;
  const int h8 = h * 8, h4 = h * 4;
  // XCD swizzle: all 8 q-blocks of a head on one XCD; heavy q-blocks first.
  const int bid = blockIdx.x;
  const int xcd = bid & 7;
  const int i = bid >> 3;            // 0..127
  const int bh = (xcd << 4) | (i & 15);
  const int qb = 7 - (i >> 4);
  const int b = bh >> 4, hh = bh & 15;
  const size_t base = (size_t)bh << 16;
  const int t0 = qb * 128 + wid * 32;
  const int qrow = t0 + l31;

  // Q as B-fragments (col=q=lane&31, k=d=16*ks+8h+j), log2-scale pre-folded
  bf16x8 qf[4];
#pragma unroll
  for (int ks = 0; ks < 4; ++ks)
    qf[ks] = *(const bf16x8*)(hq + base + (size_t)qrow * 64 + ks * 16 + h8);

  f32x16 of0, of1;
#pragma unroll
  for (int r = 0; r < 16; ++r) { of0[r] = 0.f; of1[r] = 0.f; }
  float mrun = -3.0e38f, lrun = 0.f;

  const int ntiles = qb * 4 + wid + 1;   // 32-kv tiles up to (incl.) diagonal
  for (int kt = 0; kt < ntiles; ++kt) {
    const int kvb = kt * 32;
    // ---- S^T tile: A=K rows (kv), B=Q ----
    f32x16 s;
#pragma unroll
    for (int r = 0; r < 16; ++r) s[r] = 0.f;
    __builtin_amdgcn_s_setprio(1);
#pragma unroll
    for (int ks = 0; ks < 4; ++ks) {
      bf16x8 kf = *(const bf16x8*)(hk + base + (size_t)(kvb + l31) * 64 + ks * 16 + h8);
      s = __builtin_amdgcn_mfma_f32_32x32x16_bf16(kf, qf[ks], s, 0, 0, 0);
    }
    __builtin_amdgcn_s_setprio(0);
    // causal mask on the diagonal tile only; kv = kvb + (r&3)+8*(r>>2)+4h
    if (kt == ntiles - 1) {
#pragma unroll
      for (int r = 0; r < 16; ++r) {
        int kv = kvb + (r & 3) + 8 * (r >> 2) + h4;
        if (kv > qrow) s[r] = -1.0e30f;
      }
    }
    // ---- online softmax in log2 domain; row = lane&31 (+ lane^32 half) ----
    float a0 = fmaxf(s[0], s[1]),   a1 = fmaxf(s[2], s[3]);
    float a2 = fmaxf(s[4], s[5]),   a3 = fmaxf(s[6], s[7]);
    float a4 = fmaxf(s[8], s[9]),   a5 = fmaxf(s[10], s[11]);
    float a6 = fmaxf(s[12], s[13]), a7 = fmaxf(s[14], s[15]);
    a0 = fmaxf(a0, a1); a2 = fmaxf(a2, a3); a4 = fmaxf(a4, a5); a6 = fmaxf(a6, a7);
    a0 = fmaxf(a0, a2); a4 = fmaxf(a4, a6);
    float mloc = fmaxf(a0, a4);
    mloc = fmaxf(mloc, __shfl_xor(mloc, 32));
    // defer-max (T13, THR=8 in log2 units): skip O/l rescale if growth small
    if (!__all(mloc <= mrun + 8.0f)) {
      float mnew = fmaxf(mrun, mloc);
      float alpha = __builtin_amdgcn_exp2f(mrun - mnew);
      mrun = mnew;
      lrun *= alpha;
#pragma unroll
      for (int r = 0; r < 16; ++r) { of0[r] *= alpha; of1[r] *= alpha; }
    }
    float p[16];
    float lsum = 0.f;
#pragma unroll
    for (int r = 0; r < 16; ++r) {
      p[r] = __builtin_amdgcn_exp2f(s[r] - mrun);
      lsum += p[r];
    }
    lsum += __shfl_xor(lsum, 32);
    lrun += lsum;
    // ---- P^T B-fragments: lane's own p in order (k-permutation absorbed by V)
    bf16x8 pa[2];
#pragma unroll
    for (int s2 = 0; s2 < 2; ++s2) {
      unsigned int w0 = cvt_pk_bf16(p[8 * s2 + 0], p[8 * s2 + 1]);
      unsigned int w1 = cvt_pk_bf16(p[8 * s2 + 2], p[8 * s2 + 3]);
      unsigned int w2 = cvt_pk_bf16(p[8 * s2 + 4], p[8 * s2 + 5]);
      unsigned int w3 = cvt_pk_bf16(p[8 * s2 + 6], p[8 * s2 + 7]);
      uint4 w4 = make_uint4(w0, w1, w2, w3);
      pa[s2] = __builtin_bit_cast(bf16x8, w4);
    }
    // ---- O^T += V^T * P^T with permuted k-slots on both operands ----
    __builtin_amdgcn_s_setprio(1);
#pragma unroll
    for (int s2 = 0; s2 < 2; ++s2) {
      const unsigned short* pv0 = hvt + base + (size_t)l31 * 1024        + kvb + s2 * 16 + h4;
      const unsigned short* pv1 = hvt + base + (size_t)(32 + l31) * 1024 + kvb + s2 * 16 + h4;
      uint2 a0v = *(const uint2*)(pv0);
      uint2 a1v = *(const uint2*)(pv0 + 8);
      uint2 b0v = *(const uint2*)(pv1);
      uint2 b1v = *(const uint2*)(pv1 + 8);
      bf16x8 vf0 = __builtin_bit_cast(bf16x8, make_uint4(a0v.x, a0v.y, a1v.x, a1v.y));
      bf16x8 vf1 = __builtin_bit_cast(bf16x8, make_uint4(b0v.x, b0v.y, b1v.x, b1v.y));
      of0 = __builtin_amdgcn_mfma_f32_32x32x16_bf16(vf0, pa[s2], of0, 0, 0, 0);
      of1 = __builtin_amdgcn_mfma_f32_32x32x16_bf16(vf1, pa[s2], of1, 0, 0, 0);
    }
    __builtin_amdgcn_s_setprio(0);
  }

  // ---- write vec: lane owns q-row; d = 8g + 4h + rr (of0), +32 (of1) ----
  float rl = __builtin_amdgcn_rcpf(lrun);
  unsigned short* vout = vec + ((size_t)qrow * 8 + b) * 1024 + hh * 64;
#pragma unroll
  for (int g = 0; g < 4; ++g) {
    ushort4 o;
    o.x = f2bf(of0[g * 4 + 0] * rl); o.y = f2bf(of0[g * 4 + 1] * rl);
    o.z = f2bf(of0[g * 4 + 2] * rl); o.w = f2bf(of0[g * 4 + 3] * rl);
    *(ushort4*)(vout + 8 * g + h4) = o;
    o.x = f2bf(of1[g * 4 + 0] * rl); o.y = f2bf(of1[g * 4 + 1] * rl);
    o.z = f2bf(of1[g * 4 + 2] * rl); o.w = f2bf(of1[g * 4 + 3] * rl);
    *(ushort4*)(vout + 32 + 8 * g + h4) = o;
  }
}

// ---------------- in-place LayerNorm over rows of 1024 fp32 ----------------
__global__ __launch_bounds__(256)
void ln_inplace(float* __restrict__ x, const float* __restrict__ gamma,
                const float* __restrict__ beta)
{
  __shared__ float red[2][4];
  const int tid = threadIdx.x;
  const int lane = tid & 63, wid = tid >> 6;
  const size_t row = blockIdx.x;
  float4 v = *(const float4*)(x + row * 1024 + tid * 4);
  float s = v.x + v.y + v.z + v.w;
  float q = v.x * v.x + v.y * v.y + v.z * v.z + v.w * v.w;
#pragma unroll
  for (int m = 1; m <= 32; m <<= 1) {
    s += __shfl_xor(s, m);
    q += __shfl_xor(q, m);
  }
  if (lane == 0) { red[0][wid] = s; red[1][wid] = q; }
  __syncthreads();
  float ts = red[0][0] + red[0][1] + red[0][2] + red[0][3];
  float tq = red[1][0] + red[1][1] + red[1][2] + red[1][3];
  float mu = ts * (1.0f / 1024.0f);
  float var = tq * (1.0f / 1024.0f) - mu * mu;
  float rs = rsqrtf(var + 1e-5f);
  float4 g  = *(const float4*)(gamma + tid * 4);
  float4 bt = *(const float4*)(beta + tid * 4);
  v.x = (v.x - mu) * rs * g.x + bt.x;
  v.y = (v.y - mu) * rs * g.y + bt.y;
  v.z = (v.z - mu) * rs * g.z + bt.z;
  v.w = (v.w - mu) * rs * g.w + bt.w;
  *(float4*)(x + row * 1024 + tid * 4) = v;
}

extern "C" void kernel_launch(void* const* d_in, const int* in_sizes, int n_in,
                              void* d_out, int out_size, void* d_ws, size_t ws_size,
                              hipStream_t stream) {
  const float* q     = (const float*)d_in[0];
  const float* k     = (const float*)d_in[1];
  const float* v     = (const float*)d_in[2];
  // d_in[3] = attn_mask (causal) -- analytic in-kernel
  const float* Wq    = (const float*)d_in[4];
  const float* Wk    = (const float*)d_in[5];
  const float* Wv    = (const float*)d_in[6];
  const float* Wo    = (const float*)d_in[7];
  const float* gamma = (const float*)d_in[8];
  const float* beta  = (const float*)d_in[9];

  unsigned short* ws = (unsigned short*)d_ws;
  const size_t MSZ = (size_t)8192 * 1024;
  unsigned short* hq  = ws;                 // (B,H,T,DH)
  unsigned short* hk  = ws + MSZ;           // (B,H,T,DH)
  unsigned short* hvt = ws + 2 * MSZ;       // (B,H,DH,T)
  unsigned short* tmp = ws + 3 * MSZ;       // conv buffer, then vec
  unsigned short* WqT = ws + 4 * MSZ;       // 4x [1024][1024] bf16
  unsigned short* WkT = WqT + 1048576;
  unsigned short* WvT = WqT + 2097152;
  unsigned short* WoT = WqT + 3145728;
  float* out = (float*)d_out;

  dim3 bb(256);
  dim3 gg(64, 8);
  // weights -> bf16 [n][k]; fold 1/sqrt(DH)*log2(e) into Wq -> scores in log2
  wconv<<<512, bb, 0, stream>>>(Wq, WqT, 0.125f * 1.44269504088896f);
  wconv<<<512, bb, 0, stream>>>(Wk, WkT, 1.0f);
  wconv<<<512, bb, 0, stream>>>(Wv, WvT, 1.0f);
  wconv<<<512, bb, 0, stream>>>(Wo, WoT, 1.0f);

  conv_bf16<<<4096, bb, 0, stream>>>(v, tmp);
  gemm_bf16<1><<<gg, bb, 0, stream>>>(tmp, WvT, hvt);
  conv_bf16<<<4096, bb, 0, stream>>>(q, tmp);
  gemm_bf16<0><<<gg, bb, 0, stream>>>(tmp, WqT, hq);
  conv_bf16<<<4096, bb, 0, stream>>>(k, tmp);
  gemm_bf16<0><<<gg, bb, 0, stream>>>(tmp, WkT, hk);

  flash_attn<<<1024, bb, 0, stream>>>(hq, hk, hvt, tmp);  // vec = tmp

  gemm_bf16<2><<<gg, bb, 0, stream>>>(tmp, WoT, out);
  ln_inplace<<<8192, bb, 0, stream>>>(out, gamma, beta);
}

// Round 5
// 279.689 us; speedup vs baseline: 2.1979x; 1.0310x over previous
//
#include <hip/hip_runtime.h>
#include <hip/hip_bf16.h>

// Shapes fixed by the reference: T=1024, B=8, D=1024, H=16, DH=64. M=T*B=8192.
// Intermediate layouts: hq,hk = (B,H,T,DH) bf16; hvt = (B,H,DH,T) bf16 (V^T);
// vec = row-major (M,1024) bf16 with m = t*8+b.
// Scores are produced in log2-domain: 0.125*log2(e) folded into Wq.

typedef __bf16 bf16x8 __attribute__((ext_vector_type(8)));
typedef float f32x4 __attribute__((ext_vector_type(4)));
typedef float f32x16 __attribute__((ext_vector_type(16)));
typedef unsigned short ushort8_t __attribute__((ext_vector_type(8)));

__device__ __forceinline__ unsigned short f2bf(float f) {
  unsigned int u = __builtin_bit_cast(unsigned int, f);
  u += 0x7FFFu + ((u >> 16) & 1u);   // RNE; finite inputs
  return (unsigned short)(u >> 16);
}

__device__ __forceinline__ unsigned int cvt_pk_bf16(float lo, float hi) {
  unsigned int r;
  asm("v_cvt_pk_bf16_f32 %0, %1, %2" : "=v"(r) : "v"(lo), "v"(hi));
  return r;
}

__device__ __forceinline__ void gl2lds16(const unsigned short* g, unsigned short* l) {
  __builtin_amdgcn_global_load_lds(
      (const __attribute__((address_space(1))) void*)g,
      (__attribute__((address_space(3))) void*)l, 16, 0, 0);
}

// ---------------- bf16 -> bf16 GEMM, m97 structure + LDS double-buffer -------
// A: [8192][1024] bf16 row-major. Bt: [1024][1024] bf16 = W^T ([n][k]).
// EPI 0: bf16 out at ((b*16+h)*1024+t)*64+dh   (B,H,T,DH)
// EPI 1: bf16 out at ((b*16+h)*64+dh)*1024+t   (B,H,DH,T)  [V^T]
// EPI 2: fp32 out row-major [8192][1024]
template<int EPI>
__global__ __launch_bounds__(256)
void gemm_bf16(const unsigned short* __restrict__ A,
               const unsigned short* __restrict__ Bt,
               void* __restrict__ C)
{
  __shared__ __align__(16) unsigned short As[2][128 * 64];
  __shared__ __align__(16) unsigned short Bs[2][128 * 64];
  const int tid = threadIdx.x;
  const int lane = tid & 63, wid = tid >> 6;
  const int wr = wid >> 1, wc = wid & 1;
  const int l15 = lane & 15, l4 = lane >> 4;
  const int bm = blockIdx.x, bn = blockIdx.y;

  f32x4 acc[4][4];
#pragma unroll
  for (int m = 0; m < 4; ++m)
#pragma unroll
    for (int n = 0; n < 4; ++n)
      acc[m][n] = (f32x4){0.f, 0.f, 0.f, 0.f};

  const unsigned short* ga = A  + (size_t)bm * 128 * 1024 + (tid >> 3) * 1024 + (tid & 7) * 8;
  const unsigned short* gb = Bt + (size_t)bn * 128 * 1024 + (tid >> 3) * 1024 + (tid & 7) * 8;
  const int ldsoff = wid * 512;   // wave-uniform LDS base; HW adds lane*16B

  // prologue: stage K-tile 0 into buffer 0
#pragma unroll
  for (int i = 0; i < 4; ++i) {
    gl2lds16(ga + i * 32 * 1024, &As[0][ldsoff + i * 2048]);
    gl2lds16(gb + i * 32 * 1024, &Bs[0][ldsoff + i * 2048]);
  }

  int cur = 0;
  for (int kt = 0; kt < 1024; kt += 64) {
    __syncthreads();   // buf[cur] staged (implicit vmcnt drain) + prev compute done
    if (kt + 64 < 1024) {
#pragma unroll
      for (int i = 0; i < 4; ++i) {
        gl2lds16(ga + i * 32 * 1024 + kt + 64, &As[cur ^ 1][ldsoff + i * 2048]);
        gl2lds16(gb + i * 32 * 1024 + kt + 64, &Bs[cur ^ 1][ldsoff + i * 2048]);
      }
    }
#pragma unroll
    for (int kk = 0; kk < 2; ++kk) {
      bf16x8 af[4], bfr[4];
#pragma unroll
      for (int m = 0; m < 4; ++m)
        af[m] = *(const bf16x8*)(&As[cur][(wr * 64 + m * 16 + l15) * 64 + kk * 32 + l4 * 8]);
#pragma unroll
      for (int n = 0; n < 4; ++n)
        bfr[n] = *(const bf16x8*)(&Bs[cur][(wc * 64 + n * 16 + l15) * 64 + kk * 32 + l4 * 8]);
#pragma unroll
      for (int m = 0; m < 4; ++m)
#pragma unroll
        for (int n = 0; n < 4; ++n)
          acc[m][n] = __builtin_amdgcn_mfma_f32_16x16x32_bf16(af[m], bfr[n], acc[m][n], 0, 0, 0);
    }
    cur ^= 1;
  }

#pragma unroll
  for (int m = 0; m < 4; ++m)
#pragma unroll
    for (int n = 0; n < 4; ++n)
#pragma unroll
      for (int r = 0; r < 4; ++r) {
        int row = bm * 128 + wr * 64 + m * 16 + l4 * 4 + r;   // m = t*8+b
        int col = bn * 128 + wc * 64 + n * 16 + l15;           // h*64+dh
        float v = acc[m][n][r];
        if constexpr (EPI == 2) {
          ((float*)C)[(size_t)row * 1024 + col] = v;
        } else {
          int t = row >> 3, b = row & 7;
          int h = col >> 6, dh = col & 63;
          size_t base = ((size_t)(b * 16 + h)) << 16;
          size_t idx = (EPI == 0) ? base + (size_t)t * 64 + dh
                                  : base + (size_t)dh * 1024 + t;
          ((unsigned short*)C)[idx] = f2bf(v);
        }
      }
}

// ---------------- fp32 -> bf16 convert (vectorized) ----------------
__global__ __launch_bounds__(256)
void conv_bf16(const float* __restrict__ in, unsigned short* __restrict__ out)
{
  size_t i = ((size_t)blockIdx.x * 256 + threadIdx.x) * 8;
  float4 a = *(const float4*)(in + i);
  float4 b = *(const float4*)(in + i + 4);
  ushort8_t o;
  o[0] = f2bf(a.x); o[1] = f2bf(a.y); o[2] = f2bf(a.z); o[3] = f2bf(a.w);
  o[4] = f2bf(b.x); o[5] = f2bf(b.y); o[6] = f2bf(b.z); o[7] = f2bf(b.w);
  *(ushort8_t*)(out + i) = o;
}

// ---------------- weight transpose+convert: W[k][n] fp32 -> Wt[n][k] bf16 ----
__global__ __launch_bounds__(256)
void wconv(const float* __restrict__ W, unsigned short* __restrict__ Wt, float scale)
{
  int id = blockIdx.x * 256 + threadIdx.x;
  int n = id & 1023;
  int k0 = (id >> 10) << 3;
  ushort8_t o;
#pragma unroll
  for (int j = 0; j < 8; ++j)
    o[j] = f2bf(W[(size_t)(k0 + j) * 1024 + n] * scale);
  *(ushort8_t*)(Wt + (size_t)n * 1024 + k0) = o;
}

// ---------------- causal flash attention (swapped 32x32 MFMA, no LDS) -------
// 1024 blocks x 256 threads, 4 independent waves/block, 32 q-rows per wave.
// KV chunk = 64 (two 32-kv subtiles, dual score accumulators for ILP).
// S^T = K*Q^T  -> lane holds scores of q-row (lane&31)     [C: col=lane&31]
// O^T = V^T*P^T -> lane holds O columns for same q-row     [alpha lane-local]
// PV uses k-slot permutation pi(s2,h,j)=(j&3)+8*(2*s2+(j>>2))+4h on BOTH
// operands: B-fragment = lane's own p[8*s2+j] in order (no cross-lane),
// A-fragment = V^T at kv = kvb+16*s2+4h+{0..3} and +8 (two 8B loads).
__global__ __launch_bounds__(256)
void flash_attn(const unsigned short* __restrict__ hq,
                const unsigned short* __restrict__ hk,
                const unsigned short* __restrict__ hvt,
                unsigned short* __restrict__ vec)
{
  const int tid = threadIdx.x;
  const int lane = tid & 63, wid = tid >> 6;
  const int l31 = lane & 31, h = lane >> 5;
  const int h8 = h * 8, h4 = h * 4;
  // XCD swizzle: all 8 q-blocks of a head on one XCD; heavy q-blocks first.
  const int bid = blockIdx.x;
  const int xcd = bid & 7;
  const int i = bid >> 3;            // 0..127
  const int bh = (xcd << 4) | (i & 15);
  const int qb = 7 - (i >> 4);
  const int b = bh >> 4, hh = bh & 15;
  const size_t base = (size_t)bh << 16;
  const int t0 = qb * 128 + wid * 32;
  const int qrow = t0 + l31;

  // Q as B-fragments (col=q=lane&31, k=d=16*ks+8h+j), log2-scale pre-folded
  bf16x8 qf[4];
#pragma unroll
  for (int ks = 0; ks < 4; ++ks)
    qf[ks] = *(const bf16x8*)(hq + base + (size_t)qrow * 64 + ks * 16 + h8);

  f32x16 of0, of1;
#pragma unroll
  for (int r = 0; r < 16; ++r) { of0[r] = 0.f; of1[r] = 0.f; }
  float mrun = -3.0e38f, lrun = 0.f;

  const int nchunks = (qb * 4 + wid) / 2 + 1;   // 64-kv chunks to diagonal
  for (int kt = 0; kt < nchunks; ++kt) {
    const int kvb = kt * 64;
    // ---- S^T: two 32-kv subtiles, independent accumulator chains ----
    f32x16 sa, sb;
#pragma unroll
    for (int r = 0; r < 16; ++r) { sa[r] = 0.f; sb[r] = 0.f; }
    __builtin_amdgcn_s_setprio(1);
#pragma unroll
    for (int ks = 0; ks < 4; ++ks) {
      bf16x8 kfa = *(const bf16x8*)(hk + base + (size_t)(kvb + l31) * 64      + ks * 16 + h8);
      bf16x8 kfb = *(const bf16x8*)(hk + base + (size_t)(kvb + 32 + l31) * 64 + ks * 16 + h8);
      sa = __builtin_amdgcn_mfma_f32_32x32x16_bf16(kfa, qf[ks], sa, 0, 0, 0);
      sb = __builtin_amdgcn_mfma_f32_32x32x16_bf16(kfb, qf[ks], sb, 0, 0, 0);
    }
    __builtin_amdgcn_s_setprio(0);
    // causal mask on the diagonal chunk only; kv = kvb(+32) + (r&3)+8*(r>>2)+4h
    if (kt == nchunks - 1) {
#pragma unroll
      for (int r = 0; r < 16; ++r) {
        int kv = kvb + (r & 3) + 8 * (r >> 2) + h4;
        if (kv > qrow) sa[r] = -1.0e30f;
        if (kv + 32 > qrow) sb[r] = -1.0e30f;
      }
    }
    // ---- online softmax in log2 domain; row = lane&31 (+ lane^32 half) ----
    float mx[8];
#pragma unroll
    for (int g = 0; g < 4; ++g) {
      mx[g]     = fmaxf(fmaxf(sa[4 * g], sa[4 * g + 1]), fmaxf(sa[4 * g + 2], sa[4 * g + 3]));
      mx[4 + g] = fmaxf(fmaxf(sb[4 * g], sb[4 * g + 1]), fmaxf(sb[4 * g + 2], sb[4 * g + 3]));
    }
    mx[0] = fmaxf(mx[0], mx[1]); mx[2] = fmaxf(mx[2], mx[3]);
    mx[4] = fmaxf(mx[4], mx[5]); mx[6] = fmaxf(mx[6], mx[7]);
    float mloc = fmaxf(fmaxf(mx[0], mx[2]), fmaxf(mx[4], mx[6]));
    mloc = fmaxf(mloc, __shfl_xor(mloc, 32));
    // defer-max (T13, THR=8 in log2 units): skip O/l rescale if growth small
    if (!__all(mloc <= mrun + 8.0f)) {
      float mnew = fmaxf(mrun, mloc);
      float alpha = __builtin_amdgcn_exp2f(mrun - mnew);
      mrun = mnew;
      lrun *= alpha;
#pragma unroll
      for (int r = 0; r < 16; ++r) { of0[r] *= alpha; of1[r] *= alpha; }
    }
    // ---- P = exp2(S - m), packed per 16-kv slice into B-fragments ----
    bf16x8 pa[4];
    float lsum = 0.f;
#pragma unroll
    for (int s2 = 0; s2 < 4; ++s2) {
      float p0 = __builtin_amdgcn_exp2f(((s2 < 2) ? sa[8 * s2 + 0] : sb[8 * (s2 - 2) + 0]) - mrun);
      float p1 = __builtin_amdgcn_exp2f(((s2 < 2) ? sa[8 * s2 + 1] : sb[8 * (s2 - 2) + 1]) - mrun);
      float p2 = __builtin_amdgcn_exp2f(((s2 < 2) ? sa[8 * s2 + 2] : sb[8 * (s2 - 2) + 2]) - mrun);
      float p3 = __builtin_amdgcn_exp2f(((s2 < 2) ? sa[8 * s2 + 3] : sb[8 * (s2 - 2) + 3]) - mrun);
      float p4 = __builtin_amdgcn_exp2f(((s2 < 2) ? sa[8 * s2 + 4] : sb[8 * (s2 - 2) + 4]) - mrun);
      float p5 = __builtin_amdgcn_exp2f(((s2 < 2) ? sa[8 * s2 + 5] : sb[8 * (s2 - 2) + 5]) - mrun);
      float p6 = __builtin_amdgcn_exp2f(((s2 < 2) ? sa[8 * s2 + 6] : sb[8 * (s2 - 2) + 6]) - mrun);
      float p7 = __builtin_amdgcn_exp2f(((s2 < 2) ? sa[8 * s2 + 7] : sb[8 * (s2 - 2) + 7]) - mrun);
      lsum += (p0 + p1) + (p2 + p3) + ((p4 + p5) + (p6 + p7));
      uint4 w4 = make_uint4(cvt_pk_bf16(p0, p1), cvt_pk_bf16(p2, p3),
                            cvt_pk_bf16(p4, p5), cvt_pk_bf16(p6, p7));
      pa[s2] = __builtin_bit_cast(bf16x8, w4);
    }
    lsum += __shfl_xor(lsum, 32);
    lrun += lsum;
    // ---- O^T += V^T * P^T with permuted k-slots on both operands ----
    __builtin_amdgcn_s_setprio(1);
#pragma unroll
    for (int s2 = 0; s2 < 4; ++s2) {
      const unsigned short* pv0 = hvt + base + (size_t)l31 * 1024        + kvb + s2 * 16 + h4;
      const unsigned short* pv1 = hvt + base + (size_t)(32 + l31) * 1024 + kvb + s2 * 16 + h4;
      uint2 a0v = *(const uint2*)(pv0);
      uint2 a1v = *(const uint2*)(pv0 + 8);
      uint2 b0v = *(const uint2*)(pv1);
      uint2 b1v = *(const uint2*)(pv1 + 8);
      bf16x8 vf0 = __builtin_bit_cast(bf16x8, make_uint4(a0v.x, a0v.y, a1v.x, a1v.y));
      bf16x8 vf1 = __builtin_bit_cast(bf16x8, make_uint4(b0v.x, b0v.y, b1v.x, b1v.y));
      of0 = __builtin_amdgcn_mfma_f32_32x32x16_bf16(vf0, pa[s2], of0, 0, 0, 0);
      of1 = __builtin_amdgcn_mfma_f32_32x32x16_bf16(vf1, pa[s2], of1, 0, 0, 0);
    }
    __builtin_amdgcn_s_setprio(0);
  }

  // ---- write vec: lane owns q-row; d = 8g + 4h + rr (of0), +32 (of1) ----
  float rl = __builtin_amdgcn_rcpf(lrun);
  unsigned short* vout = vec + ((size_t)qrow * 8 + b) * 1024 + hh * 64;
#pragma unroll
  for (int g = 0; g < 4; ++g) {
    ushort4 o;
    o.x = f2bf(of0[g * 4 + 0] * rl); o.y = f2bf(of0[g * 4 + 1] * rl);
    o.z = f2bf(of0[g * 4 + 2] * rl); o.w = f2bf(of0[g * 4 + 3] * rl);
    *(ushort4*)(vout + 8 * g + h4) = o;
    o.x = f2bf(of1[g * 4 + 0] * rl); o.y = f2bf(of1[g * 4 + 1] * rl);
    o.z = f2bf(of1[g * 4 + 2] * rl); o.w = f2bf(of1[g * 4 + 3] * rl);
    *(ushort4*)(vout + 32 + 8 * g + h4) = o;
  }
}

// ---------------- in-place LayerNorm over rows of 1024 fp32 ----------------
__global__ __launch_bounds__(256)
void ln_inplace(float* __restrict__ x, const float* __restrict__ gamma,
                const float* __restrict__ beta)
{
  __shared__ float red[2][4];
  const int tid = threadIdx.x;
  const int lane = tid & 63, wid = tid >> 6;
  const size_t row = blockIdx.x;
  float4 v = *(const float4*)(x + row * 1024 + tid * 4);
  float s = v.x + v.y + v.z + v.w;
  float q = v.x * v.x + v.y * v.y + v.z * v.z + v.w * v.w;
#pragma unroll
  for (int m = 1; m <= 32; m <<= 1) {
    s += __shfl_xor(s, m);
    q += __shfl_xor(q, m);
  }
  if (lane == 0) { red[0][wid] = s; red[1][wid] = q; }
  __syncthreads();
  float ts = red[0][0] + red[0][1] + red[0][2] + red[0][3];
  float tq = red[1][0] + red[1][1] + red[1][2] + red[1][3];
  float mu = ts * (1.0f / 1024.0f);
  float var = tq * (1.0f / 1024.0f) - mu * mu;
  float rs = rsqrtf(var + 1e-5f);
  float4 g  = *(const float4*)(gamma + tid * 4);
  float4 bt = *(const float4*)(beta + tid * 4);
  v.x = (v.x - mu) * rs * g.x + bt.x;
  v.y = (v.y - mu) * rs * g.y + bt.y;
  v.z = (v.z - mu) * rs * g.z + bt.z;
  v.w = (v.w - mu) * rs * g.w + bt.w;
  *(float4*)(x + row * 1024 + tid * 4) = v;
}

extern "C" void kernel_launch(void* const* d_in, const int* in_sizes, int n_in,
                              void* d_out, int out_size, void* d_ws, size_t ws_size,
                              hipStream_t stream) {
  const float* q     = (const float*)d_in[0];
  const float* k     = (const float*)d_in[1];
  const float* v     = (const float*)d_in[2];
  // d_in[3] = attn_mask (causal) -- analytic in-kernel
  const float* Wq    = (const float*)d_in[4];
  const float* Wk    = (const float*)d_in[5];
  const float* Wv    = (const float*)d_in[6];
  const float* Wo    = (const float*)d_in[7];
  const float* gamma = (const float*)d_in[8];
  const float* beta  = (const float*)d_in[9];

  unsigned short* ws = (unsigned short*)d_ws;
  const size_t MSZ = (size_t)8192 * 1024;
  unsigned short* hq  = ws;                 // (B,H,T,DH)
  unsigned short* hk  = ws + MSZ;           // (B,H,T,DH)
  unsigned short* hvt = ws + 2 * MSZ;       // (B,H,DH,T)
  unsigned short* tmp = ws + 3 * MSZ;       // conv buffer, then vec
  unsigned short* WqT = ws + 4 * MSZ;       // 4x [1024][1024] bf16
  unsigned short* WkT = WqT + 1048576;
  unsigned short* WvT = WqT + 2097152;
  unsigned short* WoT = WqT + 3145728;
  float* out = (float*)d_out;

  dim3 bb(256);
  dim3 gg(64, 8);
  // weights -> bf16 [n][k]; fold 1/sqrt(DH)*log2(e) into Wq -> scores in log2
  wconv<<<512, bb, 0, stream>>>(Wq, WqT, 0.125f * 1.44269504088896f);
  wconv<<<512, bb, 0, stream>>>(Wk, WkT, 1.0f);
  wconv<<<512, bb, 0, stream>>>(Wv, WvT, 1.0f);
  wconv<<<512, bb, 0, stream>>>(Wo, WoT, 1.0f);

  conv_bf16<<<4096, bb, 0, stream>>>(v, tmp);
  gemm_bf16<1><<<gg, bb, 0, stream>>>(tmp, WvT, hvt);
  conv_bf16<<<4096, bb, 0, stream>>>(q, tmp);
  gemm_bf16<0><<<gg, bb, 0, stream>>>(tmp, WqT, hq);
  conv_bf16<<<4096, bb, 0, stream>>>(k, tmp);
  gemm_bf16<0><<<gg, bb, 0, stream>>>(tmp, WkT, hk);

  flash_attn<<<1024, bb, 0, stream>>>(hq, hk, hvt, tmp);  // vec = tmp

  gemm_bf16<2><<<gg, bb, 0, stream>>>(tmp, WoT, out);
  ln_inplace<<<8192, bb, 0, stream>>>(out, gamma, beta);
}